// Round 1
// baseline (49.337 us; speedup 1.0000x reference)
//
#include <hip/hip_runtime.h>

// Problem constants (B=64, N=600, C=256)
#define B_DIM 64
#define N_NODES 600
#define C_DIM 256

constexpr float kThr = 0.003f;   // THRESHOLD
constexpr float kEps = 1e-7f;    // EPS

// ---------------------------------------------------------------------------
// Kernel 1: scores = x . W  (per (b,n) row), alpha_pre = exp(score) * mask
// One wave (64 lanes) per row; lane loads float4 (64*4 = 256 = C).
// ---------------------------------------------------------------------------
__global__ void k_scores(const float* __restrict__ x,
                         const float* __restrict__ W,
                         const int* __restrict__ mask,
                         float* __restrict__ alpha_pre) {
  const int row  = blockIdx.x * 4 + (threadIdx.x >> 6);  // b*N + n
  const int lane = threadIdx.x & 63;
  const float4 xv = reinterpret_cast<const float4*>(x + (size_t)row * C_DIM)[lane];
  const float4 wv = reinterpret_cast<const float4*>(W)[lane];
  float s = xv.x * wv.x + xv.y * wv.y + xv.z * wv.z + xv.w * wv.w;
  // balanced wave reduction over 64 lanes
  #pragma unroll
  for (int off = 32; off > 0; off >>= 1) s += __shfl_down(s, off, 64);
  if (lane == 0) {
    const float ap = (mask[row] != 0) ? expf(s) : 0.0f;
    alpha_pre[row] = ap;
  }
}

// ---------------------------------------------------------------------------
// Kernel 2: per-batch normalize, threshold, stable compaction index.
// One block (1024 threads) per batch b.
//   S = sum_n alpha_pre ; alpha = alpha_pre / (S + EPS)
//   keep = mask && alpha > THR
//   idx[pos] = n  with pos = keep ? excl_prefix(keep) : K + excl_prefix(!keep)
//   mask_out[i] = (i < K)
// ---------------------------------------------------------------------------
__global__ void k_compact(const int* __restrict__ mask,
                          float* __restrict__ alpha,     // in: alpha_pre, out: alpha
                          int* __restrict__ idx,
                          int* __restrict__ Kbuf,
                          float* __restrict__ mask_out) {
  const int b = blockIdx.x;
  const int t = threadIdx.x;  // 0..1023

  __shared__ float fs[1024];
  __shared__ int   sbuf[2][1024];

  const float ap = (t < N_NODES) ? alpha[b * N_NODES + t] : 0.0f;

  // --- tree-reduce sum (balanced, close to numpy pairwise order) ---
  fs[t] = ap;
  __syncthreads();
  #pragma unroll
  for (int off = 512; off > 0; off >>= 1) {
    if (t < off) fs[t] += fs[t + off];
    __syncthreads();
  }
  const float S = fs[0];

  const float a = ap / (S + kEps);
  const int   m = (t < N_NODES) ? mask[b * N_NODES + t] : 0;
  const int keep = (m != 0 && a > kThr) ? 1 : 0;
  if (t < N_NODES) alpha[b * N_NODES + t] = a;

  // --- Hillis-Steele inclusive scan of keep ---
  int pin = 0;
  sbuf[0][t] = keep;
  __syncthreads();
  #pragma unroll
  for (int off = 1; off < 1024; off <<= 1) {
    int v = sbuf[pin][t];
    if (t >= off) v += sbuf[pin][t - off];
    sbuf[pin ^ 1][t] = v;
    pin ^= 1;
    __syncthreads();
  }
  const int incl = sbuf[pin][t];
  const int K    = sbuf[pin][1023];  // threads >= N contribute keep=0

  if (t < N_NODES) {
    const int pos = keep ? (incl - 1) : (K + (t - incl));
    idx[b * N_NODES + pos] = t;
    mask_out[b * N_NODES + t] = (t < K) ? 1.0f : 0.0f;
    if (t == 0) Kbuf[b] = K;
  }
}

// ---------------------------------------------------------------------------
// Kernel 3: x_out[b,i,:] = x[b, idx[b,i], :] * alpha[b, idx[b,i]]
// One wave per output row, float4.
// ---------------------------------------------------------------------------
__global__ void k_gather_x(const float* __restrict__ x,
                           const float* __restrict__ alpha,
                           const int* __restrict__ idx,
                           float* __restrict__ xo) {
  const int row  = blockIdx.x * 4 + (threadIdx.x >> 6);  // b*N + i
  const int lane = threadIdx.x & 63;
  const int b = row / N_NODES;
  const int src = idx[row];
  const float a = alpha[b * N_NODES + src];
  float4 v = reinterpret_cast<const float4*>(
      x + ((size_t)b * N_NODES + src) * C_DIM)[lane];
  v.x *= a; v.y *= a; v.z *= a; v.w *= a;
  reinterpret_cast<float4*>(xo + (size_t)row * C_DIM)[lane] = v;
}

// ---------------------------------------------------------------------------
// Kernel 4: A_out[b,i,j] = (i<K && j<K) ? A[b, idx[i], idx[j]] : 0
// Block handles 8 consecutive output rows of one batch; idx row staged in LDS.
// ---------------------------------------------------------------------------
#define TILE_I 8
__global__ void k_gather_A(const float* __restrict__ A,
                           const int* __restrict__ idx,
                           const int* __restrict__ Kbuf,
                           float* __restrict__ Ao) {
  __shared__ int sidx[N_NODES];
  const int bi = blockIdx.x;
  const int b  = bi / (N_NODES / TILE_I);
  const int i0 = (bi % (N_NODES / TILE_I)) * TILE_I;
  const int t  = threadIdx.x;  // 0..255

  for (int j = t; j < N_NODES; j += 256) sidx[j] = idx[b * N_NODES + j];
  __syncthreads();
  const int K = Kbuf[b];

  const float* Ab  = A  + (size_t)b * N_NODES * N_NODES;
  float*       Aob = Ao + (size_t)b * N_NODES * N_NODES;

  #pragma unroll
  for (int ii = 0; ii < TILE_I; ++ii) {
    const int i = i0 + ii;
    float* Aorow = Aob + (size_t)i * N_NODES;
    if (i < K) {
      const float* Arow = Ab + (size_t)sidx[i] * N_NODES;
      for (int j = t; j < N_NODES; j += 256)
        Aorow[j] = (j < K) ? Arow[sidx[j]] : 0.0f;
    } else {
      for (int j = t; j < N_NODES; j += 256) Aorow[j] = 0.0f;
    }
  }
}

// ---------------------------------------------------------------------------
extern "C" void kernel_launch(void* const* d_in, const int* in_sizes, int n_in,
                              void* d_out, int out_size, void* d_ws, size_t ws_size,
                              hipStream_t stream) {
  const float* x    = (const float*)d_in[0];
  const float* A    = (const float*)d_in[1];
  const int*   mask = (const int*)d_in[2];
  const float* W    = (const float*)d_in[3];

  const size_t BN = (size_t)B_DIM * N_NODES;

  float* xo = (float*)d_out;                       // (B,N,C)
  float* Ao = xo + BN * C_DIM;                     // (B,N,N)
  float* mo = Ao + BN * N_NODES;                   // (B,N) as 0.0/1.0

  // workspace layout
  float* alpha = (float*)d_ws;                     // B*N floats
  int*   idx   = (int*)(alpha + BN);               // B*N ints
  int*   Kbuf  = idx + BN;                         // B ints

  // 1. scores -> alpha_pre
  k_scores<<<(int)(BN / 4), 256, 0, stream>>>(x, W, mask, alpha);
  // 2. normalize + compaction index
  k_compact<<<B_DIM, 1024, 0, stream>>>(mask, alpha, idx, Kbuf, mo);
  // 3. gather x
  k_gather_x<<<(int)(BN / 4), 256, 0, stream>>>(x, alpha, idx, xo);
  // 4. gather A
  k_gather_A<<<B_DIM * (N_NODES / TILE_I), 256, 0, stream>>>(A, idx, Kbuf, Ao);
}